// Round 20
// baseline (21.244 us; speedup 1.0000x reference)
//
#include <hip/hip_runtime.h>

#define NQ 4
#define NL 4

typedef _Float16 f16x8 __attribute__((ext_vector_type(8)));
typedef float f32x16 __attribute__((ext_vector_type(16)));
typedef float f32x4  __attribute__((ext_vector_type(4)));

#define INV2PI 0.15915494309189535f
#define CHUNKS 4
#define CSAMP  256          // samples per chunk (= block size)

// LDS-only barrier (R17): waits ds ops, not VMEM.
#define LGKM_BARRIER() do {                                   \
    asm volatile("s_waitcnt lgkmcnt(0)" ::: "memory");        \
    __builtin_amdgcn_sched_barrier(0);                        \
    __builtin_amdgcn_s_barrier();                             \
    __builtin_amdgcn_sched_barrier(0);                        \
  } while (0)

// ---------------------------------------------------------------------------
// R18 base (18.76 us), single change: NONTEMPORAL x loads. The harness's
// 268 MB poison fills leave L3 entirely dirty; every cold allocation
// (read or write) evicts a dirty line to HBM -> ~56 MB hidden write
// amplification (~9 us). NT stores fixed the out side (R16, +2 us); this
// extends the bypass to the 16 MB x read stream.
// ---------------------------------------------------------------------------
__global__ __launch_bounds__(256) void qnn_fused(
    const float*  __restrict__ x,     // [B*4]
    const float*  __restrict__ w,     // [4][4][3]
    const float*  __restrict__ fcw,   // [10][4]
    const float*  __restrict__ fcb,   // [10]
    float*        __restrict__ out,   // [B*10]
    int nB)
{
  __shared__ float sM[512];               // M[32][16]
  __shared__ float sG[512];               // G[32][16]
  __shared__ float obuf[2][CSAMP * 10];   // 20 KB double-buffered output

  int t    = threadIdx.x;
  int lane = t & 63;
  int wv   = t >> 6;
  int col  = lane & 31;
  int hi   = lane >> 5;

  int base = blockIdx.x * (CHUNKS * CSAMP);

  // ---- issue ALL x loads first (nontemporal: no L3 allocation) ----
  f32x4 xv[CHUNKS][2];
#pragma unroll
  for (int c = 0; c < CHUNKS; ++c) {
#pragma unroll
    for (int g = 0; g < 2; ++g) {
      int s = base + c * CSAMP + wv * 64 + g * 32 + col;
      s = (s < nB) ? s : (nB - 1);
      xv[c][g] = __builtin_nontemporal_load((const f32x4*)(x + (size_t)s * 4));
    }
  }

  // ================= parallel prelude (native trig) =================
  {
    int k = t >> 4;        // basis column 0..15
    int j = t & 15;        // state row 0..15
    int gbase = lane & 48; // lane group base for shfl

    float re = (j == k) ? 1.f : 0.f;
    float im = 0.f;

    const int ranges[4] = {1, 2, 3, 1};
#pragma unroll
    for (int l = 0; l < NL; ++l) {
#pragma unroll
      for (int q = 0; q < NQ; ++q) {
        float phi = w[l*12 + q*3 + 0];
        float th  = w[l*12 + q*3 + 1];
        float om  = w[l*12 + q*3 + 2];
        float at = th * (0.5f * INV2PI);
        float st = __builtin_amdgcn_sinf(at), ct = __builtin_amdgcn_cosf(at);
        float ap = (phi + om) * (0.5f * INV2PI);
        float spo = __builtin_amdgcn_sinf(ap), cpo = __builtin_amdgcn_cosf(ap);
        float am = (phi - om) * (0.5f * INV2PI);
        float smo = __builtin_amdgcn_sinf(am), cmo = __builtin_amdgcn_cosf(am);

        float ar = cpo*ct,  ai = -spo*ct;
        float br = -cmo*st, bi = -smo*st;
        float dr = cmo*st,  di = -smo*st;
        float er = cpo*ct,  ei = spo*ct;

        int m = 8 >> q;
        float pre = __shfl_xor(re, m);
        float pim = __shfl_xor(im, m);
        bool one = (j & m) != 0;
        float scr = one ? er : ar, sci = one ? ei : ai;
        float pcr = one ? dr : br, pci = one ? di : bi;
        float nre = scr*re - sci*im + pcr*pre - pci*pim;
        float nim = scr*im + sci*re + pcr*pim + pci*pre;
        re = nre; im = nim;
      }
      int r = ranges[l];
      int src = j;
#pragma unroll
      for (int q = 3; q >= 0; --q) {
        int mc = 8 >> q;
        int mt = 8 >> ((q + r) & 3);
        src ^= (src & mc) ? mt : 0;
      }
      re = __shfl(re, gbase + src);
      im = __shfl(im, gbase + src);
    }

    int pc = __popc(k) & 3;
    float re2, im2;
    if      (pc == 0) { re2 =  re; im2 =  im; }
    else if (pc == 1) { re2 =  im; im2 = -re; }
    else if (pc == 2) { re2 = -re; im2 = -im; }
    else              { re2 = -im; im2 =  re; }
    sM[j*16 + k]        = re2;
    sM[(16 + j)*16 + k] = im2;

    if (t < 160) {
      int o  = t >> 4;
      int kk = t & 15;
      int jj = (kk & 3) + 8 * ((kk >> 2) & 1) + 4 * (kk >> 3);
      float g = fcw[o*4 + 0] * ((jj & 8) ? -1.f : 1.f)
              + fcw[o*4 + 1] * ((jj & 4) ? -1.f : 1.f)
              + fcw[o*4 + 2] * ((jj & 2) ? -1.f : 1.f)
              + fcw[o*4 + 3] * ((jj & 1) ? -1.f : 1.f);
      sG[t] = g;
    }
    for (int i = t; i < 352; i += 256) sG[160 + i] = 0.f;
  }
  __syncthreads();

  // ---- build fragments from LDS (split-f16 M, plain-f16 G) ----
  int row = col;
  int k0  = hi * 8;
  f16x8 Ahi, Alo, Ghi;
#pragma unroll
  for (int i = 0; i < 8; ++i) {
    float v = sM[row * 16 + k0 + i];
    _Float16 h = (_Float16)v;
    Ahi[i] = h;
    Alo[i] = (_Float16)(v - (float)h);
    Ghi[i] = (_Float16)sG[row * 16 + k0 + i];
  }

  // bias: acc2 rows for this lane: hi=0 -> {0,1,2,3,8,9}, hi=1 -> {4,5,6,7}
  int o0 = hi * 4;
  float b0 = fcb[o0 + 0], b1 = fcb[o0 + 1], b2 = fcb[o0 + 2], b3 = fcb[o0 + 3];
  float b4 = hi ? 0.f : fcb[8];
  float b5 = hi ? 0.f : fcb[9];

  int lim = nB * 10;

#pragma unroll
  for (int c = 0; c < CHUNKS; ++c) {
    float* ob = obuf[c & 1];

    // compute 2 MFMA groups (64 samples per wave), x straight from VGPRs
#pragma unroll
    for (int g = 0; g < 2; ++g) {
      int sl = wv * 64 + g * 32 + col;
      f32x4 x4 = xv[c][g];

      float rev0 = x4[0] * (0.5f * INV2PI);
      float cs0  = __builtin_amdgcn_sinf(hi ? rev0 : rev0 + 0.25f);
      float rev1 = x4[1] * (0.5f * INV2PI);
      float s1 = __builtin_amdgcn_sinf(rev1), c1 = __builtin_amdgcn_cosf(rev1);
      float rev2 = x4[2] * (0.5f * INV2PI);
      float s2 = __builtin_amdgcn_sinf(rev2), c2 = __builtin_amdgcn_cosf(rev2);
      float rev3 = x4[3] * (0.5f * INV2PI);
      float s3 = __builtin_amdgcn_sinf(rev3), c3 = __builtin_amdgcn_cosf(rev3);

      float a0 = cs0 * c1, a1 = cs0 * s1;
      float w0 = c2 * c3, w1 = c2 * s3, w2 = s2 * c3, w3 = s2 * s3;
      f16x8 Bf;
      Bf[0] = (_Float16)(a0 * w0); Bf[1] = (_Float16)(a0 * w1);
      Bf[2] = (_Float16)(a0 * w2); Bf[3] = (_Float16)(a0 * w3);
      Bf[4] = (_Float16)(a1 * w0); Bf[5] = (_Float16)(a1 * w1);
      Bf[6] = (_Float16)(a1 * w2); Bf[7] = (_Float16)(a1 * w3);

      f32x16 acc = {0.f,0.f,0.f,0.f,0.f,0.f,0.f,0.f,
                    0.f,0.f,0.f,0.f,0.f,0.f,0.f,0.f};
      acc = __builtin_amdgcn_mfma_f32_32x32x16_f16(Ahi, Bf, acc, 0, 0, 0);
      acc = __builtin_amdgcn_mfma_f32_32x32x16_f16(Alo, Bf, acc, 0, 0, 0);

      f16x8 Bp;
      Bp[0] = (_Float16)fmaf(acc[0], acc[0], acc[8]  * acc[8]);
      Bp[1] = (_Float16)fmaf(acc[1], acc[1], acc[9]  * acc[9]);
      Bp[2] = (_Float16)fmaf(acc[2], acc[2], acc[10] * acc[10]);
      Bp[3] = (_Float16)fmaf(acc[3], acc[3], acc[11] * acc[11]);
      Bp[4] = (_Float16)fmaf(acc[4], acc[4], acc[12] * acc[12]);
      Bp[5] = (_Float16)fmaf(acc[5], acc[5], acc[13] * acc[13]);
      Bp[6] = (_Float16)fmaf(acc[6], acc[6], acc[14] * acc[14]);
      Bp[7] = (_Float16)fmaf(acc[7], acc[7], acc[15] * acc[15]);

      f32x16 acc2 = {b0, b1, b2, b3, b4, b5, 0.f, 0.f,
                     0.f, 0.f, 0.f, 0.f, 0.f, 0.f, 0.f, 0.f};
      acc2 = __builtin_amdgcn_mfma_f32_32x32x16_f16(Ghi, Bp, acc2, 0, 0, 0);

      float2 v01; v01.x = acc2[0]; v01.y = acc2[1];
      float2 v23; v23.x = acc2[2]; v23.y = acc2[3];
      *(float2*)&ob[sl * 10 + o0]     = v01;
      *(float2*)&ob[sl * 10 + o0 + 2] = v23;
      if (!hi) {
        float2 v89; v89.x = acc2[4]; v89.y = acc2[5];
        *(float2*)&ob[sl * 10 + 8] = v89;
      }
    }

    LGKM_BARRIER();    // obuf[c&1] handoff; VMEM stays in flight

    // bulk coalesced NONTEMPORAL store: 2560 floats = 640 dwordx4
    int cb = base * 10 + c * (CSAMP * 10);
#pragma unroll
    for (int i = 0; i < 3; ++i) {
      int idx = t + i * 256;
      if (idx < 640) {
        int gidx = cb + idx * 4;
        if (gidx < lim) {
          f32x4 v = *(f32x4*)&ob[idx * 4];
          __builtin_nontemporal_store(v, (f32x4*)&out[gidx]);
        }
      }
    }
  }
}

extern "C" void kernel_launch(void* const* d_in, const int* in_sizes, int n_in,
                              void* d_out, int out_size, void* d_ws, size_t ws_size,
                              hipStream_t stream) {
  const float* x   = (const float*)d_in[0];
  const float* w   = (const float*)d_in[1];
  const float* fcw = (const float*)d_in[2];
  const float* fcb = (const float*)d_in[3];
  float* out = (float*)d_out;
  int nB = in_sizes[0] / 4;

  int nblk = (nB + CHUNKS * CSAMP - 1) / (CHUNKS * CSAMP);
  hipLaunchKernelGGL(qnn_fused, dim3(nblk), dim3(256), 0, stream,
                     x, w, fcw, fcb, out, nB);
}

// Round 21
// 18.678 us; speedup vs baseline: 1.1374x; 1.1374x over previous
//
#include <hip/hip_runtime.h>

#define NQ 4
#define NL 4

typedef _Float16 f16x8 __attribute__((ext_vector_type(8)));
typedef float f32x16 __attribute__((ext_vector_type(16)));
typedef float f32x4  __attribute__((ext_vector_type(4)));
typedef float f32x2  __attribute__((ext_vector_type(2)));

#define INV2PI 0.15915494309189535f
#define CHUNKS 4
#define CSAMP  256          // samples per chunk (= block size)

// ---------------------------------------------------------------------------
// R18 base (18.76 us), single change: obuf deleted. Each lane NT-stores its
// sample's outputs directly (f32x2 pieces, 8B aligned). Zero barriers in the
// main loop -> no wave lockstep, store stream starts at chunk 0 and never
// drains until kernel end. (Clean A/B vs R18: staging round-trip + barrier
// cost vs scattered-8B-store cost.)
// ---------------------------------------------------------------------------
__global__ __launch_bounds__(256) void qnn_fused(
    const float4* __restrict__ x,     // [B]
    const float*  __restrict__ w,     // [4][4][3]
    const float*  __restrict__ fcw,   // [10][4]
    const float*  __restrict__ fcb,   // [10]
    float*        __restrict__ out,   // [B*10]
    int nB)
{
  __shared__ float sM[512];               // M[32][16]
  __shared__ float sG[512];               // G[32][16]

  int t    = threadIdx.x;
  int lane = t & 63;
  int wv   = t >> 6;
  int col  = lane & 31;
  int hi   = lane >> 5;

  int base = blockIdx.x * (CHUNKS * CSAMP);

  // ---- issue ALL x loads first; latency hides under the prelude ----
  float4 xv[CHUNKS][2];
#pragma unroll
  for (int c = 0; c < CHUNKS; ++c) {
#pragma unroll
    for (int g = 0; g < 2; ++g) {
      int s = base + c * CSAMP + wv * 64 + g * 32 + col;
      xv[c][g] = x[(s < nB) ? s : (nB - 1)];
    }
  }

  // ================= parallel prelude (native trig) =================
  {
    int k = t >> 4;        // basis column 0..15
    int j = t & 15;        // state row 0..15
    int gbase = lane & 48; // lane group base for shfl

    float re = (j == k) ? 1.f : 0.f;
    float im = 0.f;

    const int ranges[4] = {1, 2, 3, 1};
#pragma unroll
    for (int l = 0; l < NL; ++l) {
#pragma unroll
      for (int q = 0; q < NQ; ++q) {
        float phi = w[l*12 + q*3 + 0];
        float th  = w[l*12 + q*3 + 1];
        float om  = w[l*12 + q*3 + 2];
        float at = th * (0.5f * INV2PI);
        float st = __builtin_amdgcn_sinf(at), ct = __builtin_amdgcn_cosf(at);
        float ap = (phi + om) * (0.5f * INV2PI);
        float spo = __builtin_amdgcn_sinf(ap), cpo = __builtin_amdgcn_cosf(ap);
        float am = (phi - om) * (0.5f * INV2PI);
        float smo = __builtin_amdgcn_sinf(am), cmo = __builtin_amdgcn_cosf(am);

        float ar = cpo*ct,  ai = -spo*ct;
        float br = -cmo*st, bi = -smo*st;
        float dr = cmo*st,  di = -smo*st;
        float er = cpo*ct,  ei = spo*ct;

        int m = 8 >> q;
        float pre = __shfl_xor(re, m);
        float pim = __shfl_xor(im, m);
        bool one = (j & m) != 0;
        float scr = one ? er : ar, sci = one ? ei : ai;
        float pcr = one ? dr : br, pci = one ? di : bi;
        float nre = scr*re - sci*im + pcr*pre - pci*pim;
        float nim = scr*im + sci*re + pcr*pim + pci*pre;
        re = nre; im = nim;
      }
      int r = ranges[l];
      int src = j;
#pragma unroll
      for (int q = 3; q >= 0; --q) {
        int mc = 8 >> q;
        int mt = 8 >> ((q + r) & 3);
        src ^= (src & mc) ? mt : 0;
      }
      re = __shfl(re, gbase + src);
      im = __shfl(im, gbase + src);
    }

    int pc = __popc(k) & 3;
    float re2, im2;
    if      (pc == 0) { re2 =  re; im2 =  im; }
    else if (pc == 1) { re2 =  im; im2 = -re; }
    else if (pc == 2) { re2 = -re; im2 = -im; }
    else              { re2 = -im; im2 =  re; }
    sM[j*16 + k]        = re2;
    sM[(16 + j)*16 + k] = im2;

    if (t < 160) {
      int o  = t >> 4;
      int kk = t & 15;
      int jj = (kk & 3) + 8 * ((kk >> 2) & 1) + 4 * (kk >> 3);
      float g = fcw[o*4 + 0] * ((jj & 8) ? -1.f : 1.f)
              + fcw[o*4 + 1] * ((jj & 4) ? -1.f : 1.f)
              + fcw[o*4 + 2] * ((jj & 2) ? -1.f : 1.f)
              + fcw[o*4 + 3] * ((jj & 1) ? -1.f : 1.f);
      sG[t] = g;
    }
    for (int i = t; i < 352; i += 256) sG[160 + i] = 0.f;
  }
  __syncthreads();

  // ---- build fragments from LDS (split-f16 M, plain-f16 G) ----
  int row = col;
  int k0  = hi * 8;
  f16x8 Ahi, Alo, Ghi;
#pragma unroll
  for (int i = 0; i < 8; ++i) {
    float v = sM[row * 16 + k0 + i];
    _Float16 h = (_Float16)v;
    Ahi[i] = h;
    Alo[i] = (_Float16)(v - (float)h);
    Ghi[i] = (_Float16)sG[row * 16 + k0 + i];
  }

  // bias: acc2 rows for this lane: hi=0 -> {0,1,2,3,8,9}, hi=1 -> {4,5,6,7}
  int o0 = hi * 4;
  float b0 = fcb[o0 + 0], b1 = fcb[o0 + 1], b2 = fcb[o0 + 2], b3 = fcb[o0 + 3];
  float b4 = hi ? 0.f : fcb[8];
  float b5 = hi ? 0.f : fcb[9];

#pragma unroll
  for (int c = 0; c < CHUNKS; ++c) {
#pragma unroll
    for (int g = 0; g < 2; ++g) {
      int sl = wv * 64 + g * 32 + col;
      int s  = base + c * CSAMP + sl;
      float4 x4 = xv[c][g];

      float rev0 = x4.x * (0.5f * INV2PI);
      float cs0  = __builtin_amdgcn_sinf(hi ? rev0 : rev0 + 0.25f);
      float rev1 = x4.y * (0.5f * INV2PI);
      float s1 = __builtin_amdgcn_sinf(rev1), c1 = __builtin_amdgcn_cosf(rev1);
      float rev2 = x4.z * (0.5f * INV2PI);
      float s2 = __builtin_amdgcn_sinf(rev2), c2 = __builtin_amdgcn_cosf(rev2);
      float rev3 = x4.w * (0.5f * INV2PI);
      float s3 = __builtin_amdgcn_sinf(rev3), c3 = __builtin_amdgcn_cosf(rev3);

      float a0 = cs0 * c1, a1 = cs0 * s1;
      float w0 = c2 * c3, w1 = c2 * s3, w2 = s2 * c3, w3 = s2 * s3;
      f16x8 Bf;
      Bf[0] = (_Float16)(a0 * w0); Bf[1] = (_Float16)(a0 * w1);
      Bf[2] = (_Float16)(a0 * w2); Bf[3] = (_Float16)(a0 * w3);
      Bf[4] = (_Float16)(a1 * w0); Bf[5] = (_Float16)(a1 * w1);
      Bf[6] = (_Float16)(a1 * w2); Bf[7] = (_Float16)(a1 * w3);

      f32x16 acc = {0.f,0.f,0.f,0.f,0.f,0.f,0.f,0.f,
                    0.f,0.f,0.f,0.f,0.f,0.f,0.f,0.f};
      acc = __builtin_amdgcn_mfma_f32_32x32x16_f16(Ahi, Bf, acc, 0, 0, 0);
      acc = __builtin_amdgcn_mfma_f32_32x32x16_f16(Alo, Bf, acc, 0, 0, 0);

      f16x8 Bp;
      Bp[0] = (_Float16)fmaf(acc[0], acc[0], acc[8]  * acc[8]);
      Bp[1] = (_Float16)fmaf(acc[1], acc[1], acc[9]  * acc[9]);
      Bp[2] = (_Float16)fmaf(acc[2], acc[2], acc[10] * acc[10]);
      Bp[3] = (_Float16)fmaf(acc[3], acc[3], acc[11] * acc[11]);
      Bp[4] = (_Float16)fmaf(acc[4], acc[4], acc[12] * acc[12]);
      Bp[5] = (_Float16)fmaf(acc[5], acc[5], acc[13] * acc[13]);
      Bp[6] = (_Float16)fmaf(acc[6], acc[6], acc[14] * acc[14]);
      Bp[7] = (_Float16)fmaf(acc[7], acc[7], acc[15] * acc[15]);

      f32x16 acc2 = {b0, b1, b2, b3, b4, b5, 0.f, 0.f,
                     0.f, 0.f, 0.f, 0.f, 0.f, 0.f, 0.f, 0.f};
      acc2 = __builtin_amdgcn_mfma_f32_32x32x16_f16(Ghi, Bp, acc2, 0, 0, 0);

      if (s < nB) {
        float* op = out + (size_t)s * 10 + o0;   // 8B-aligned
        f32x2 v01; v01[0] = acc2[0]; v01[1] = acc2[1];
        f32x2 v23; v23[0] = acc2[2]; v23[1] = acc2[3];
        __builtin_nontemporal_store(v01, (f32x2*)(op + 0));
        __builtin_nontemporal_store(v23, (f32x2*)(op + 2));
        if (!hi) {
          f32x2 v89; v89[0] = acc2[4]; v89[1] = acc2[5];
          __builtin_nontemporal_store(v89, (f32x2*)(out + (size_t)s * 10 + 8));
        }
      }
    }
  }
}

extern "C" void kernel_launch(void* const* d_in, const int* in_sizes, int n_in,
                              void* d_out, int out_size, void* d_ws, size_t ws_size,
                              hipStream_t stream) {
  const float* x   = (const float*)d_in[0];
  const float* w   = (const float*)d_in[1];
  const float* fcw = (const float*)d_in[2];
  const float* fcb = (const float*)d_in[3];
  float* out = (float*)d_out;
  int nB = in_sizes[0] / 4;

  int nblk = (nB + CHUNKS * CSAMP - 1) / (CHUNKS * CSAMP);
  hipLaunchKernelGGL(qnn_fused, dim3(nblk), dim3(256), 0, stream,
                     (const float4*)x, w, fcw, fcb, out, nB);
}